// Round 14
// baseline (346.423 us; speedup 1.0000x reference)
//
#include <hip/hip_runtime.h>
#include <math.h>

// Problem constants (from reference)
constexpr int cS  = 16;   // sequence
constexpr int cB  = 8;    // batch
constexpr int cNC = 5;    // classes
constexpr int cD  = 256;  // hidden
constexpr int cP  = 16;   // patches
constexpr int cPD = 49;   // patch dim
#define LEPS 1e-5f

__device__ __forceinline__ float frcp(float x) { return __builtin_amdgcn_rcpf(x); }
__device__ __forceinline__ float sigm(float x) { return frcp(1.0f + __expf(-x)); }
__device__ __forceinline__ float gelu_t(float x) {
  const float z = 1.5957691216057308f * (x + 0.044715f * x * x * x);
  return x * frcp(1.0f + __expf(-z));
}

// ---- DPP 16-lane reductions (reductions only; matvec broadcasts stay on the
// ---- DS pipe via __shfl which overlaps with VALU — R12 lesson).
template<int CTRL>
__device__ __forceinline__ float dpp_mov(float v) {
  return __int_as_float(__builtin_amdgcn_update_dpp(
      0, __float_as_int(v), CTRL, 0xF, 0xF, true));
}
__device__ __forceinline__ float row_sum16(float v) {
  v += dpp_mov<0xB1>(v);
  v += dpp_mov<0x4E>(v);
  v += dpp_mov<0x124>(v);
  v += dpp_mov<0x128>(v);
  return v;
}
__device__ __forceinline__ float wave_sum64(float v) {
  v = row_sum16(v);
  v += __shfl_xor(v, 16, 64);
  v += __shfl_xor(v, 32, 64);
  return v;
}

// ---- SRWM step (shuffle broadcasts, deferred softmax normalize)
__device__ __forceinline__ float srwm_step(
    float xv, float (&wy)[16], float (&wq)[16], float (&wk)[16], float (&wbr)[16]) {
  float y = 0.f, q = 0.f, k = 0.f, bt = 0.f;
#pragma unroll
  for (int j = 0; j < 16; ++j) {
    const float xj = __shfl(xv, j, 16);
    y += wy[j] * xj; q += wq[j] * xj; k += wk[j] * xj; bt += wbr[j] * xj;
  }
  const float bsig = sigm(bt);
  const float eq = __expf(q), ek = __expf(k);
  float ay = 0.f, vyk = 0.f, vqq = 0.f, vqk = 0.f, vkq = 0.f, vkk = 0.f, vbq = 0.f, vbk = 0.f;
  float ksj[16];
#pragma unroll
  for (int j = 0; j < 16; ++j) {
    const float qj = __shfl(eq, j, 16);
    const float kj = __shfl(ek, j, 16);
    ksj[j] = kj;
    ay  += wy[j]  * qj; vyk += wy[j]  * kj;
    vqq += wq[j]  * qj; vqk += wq[j]  * kj;
    vkq += wk[j]  * qj; vkk += wk[j]  * kj;
    vbq += wbr[j] * qj; vbk += wbr[j] * kj;
  }
  const float rq = frcp(row_sum16(eq));
  const float rk = frcp(row_sum16(ek));
  const float ea = __expf(ay * rq);
  const float vyq = ea * frcp(row_sum16(ea));
  const float b0  = __shfl(bsig, 0, 16);
  const float b1v = __shfl(bsig, 1, 16);
  const float b2v = __shfl(bsig, 2, 16);
  const float b3v = __shfl(bsig, 3, 16);
  const float cy = b0  * (vyq      - vyk * rk) * rk;
  const float cq = b1v * (vqq * rq - vqk * rk) * rk;
  const float ck = b2v * (vkq * rq - vkk * rk) * rk;
  const float cb = b3v * (vbq * rq - vbk * rk) * rk;
#pragma unroll
  for (int j = 0; j < 16; ++j) {
    wy[j] += cy * ksj[j]; wq[j] += cq * ksj[j]; wk[j] += ck * ksj[j]; wbr[j] += cb * ksj[j];
  }
  return y;
}

// --------- token SRWM (+ fused embed on layer 0): 256 blocks x 128 ---------
// we==1: all 16 images of this block's b staged to LDS ONCE (one barrier),
// inW rows hoisted to registers, xp computed in-kernel (embed never hits HBM).
__global__ __launch_bounds__(128, 1) void k_tok_srwm(
    float* __restrict__ h, const float* __restrict__ Wy0, const float* __restrict__ Wq0,
    const float* __restrict__ Wk0, const float* __restrict__ wb0,
    const float* __restrict__ lng, const float* __restrict__ lnb,
    int we, const float* __restrict__ x, const int* __restrict__ fb,
    const float* __restrict__ inW, const float* __restrict__ inb) {
  const int t    = threadIdx.x;
  const int lane = t & 63;
  const int w    = t >> 6;              // 0..1
  const int r    = lane & 15;
  const int li   = lane >> 4;
  const int b    = blockIdx.x >> 5;     // 8 b x 32 dgroups
  const int d    = ((blockIdx.x & 31) << 3) + (w << 2) + li;
  __shared__ float img[cS * 784];       // 50 KB, loaded once (layer 0 only)
  float wy[16], wq[16], wk[16], wbr[16];
#pragma unroll
  for (int j = 0; j < 16; ++j) {
    wy[j]  = Wy0[r * 16 + j];
    wq[j]  = Wq0[r * 16 + j];
    wk[j]  = Wk0[r * 16 + j];
    wbr[j] = wb0[(r & 3) * 16 + j];
  }
  const float gg = lng[r], bb = lnb[r];
  float xp[16];
  if (we) {
    // stage 16 images (this b) to LDS, coalesced
    for (int idx = t; idx < cS * 784; idx += 128) {
      const int s = idx / 784, pix = idx % 784;
      img[idx] = x[(size_t)(s * cB + b) * 784 + pix];
    }
    float winreg[cPD];
#pragma unroll
    for (int j = 0; j < cPD; ++j) winreg[j] = inW[(size_t)j * cD + d];
    const float ib = inb[d];
    const int pixbase = (r >> 2) * 196 + (r & 3) * 7;   // ph*7*28 + pw*7
    __syncthreads();
#pragma unroll
    for (int s = 0; s < cS; ++s) {
      const int cls = fb[s * cB + b];
      float acc = ib + inW[(size_t)(cPD + cls) * cD + d];
#pragma unroll
      for (int j = 0; j < cPD; ++j)
        acc += img[s * 784 + pixbase + (j / 7) * 28 + (j % 7)] * winreg[j];
      xp[s] = acc;
    }
  } else {
#pragma unroll
    for (int s = 0; s < 16; ++s)
      xp[s] = h[((size_t)(s * cB + b) * cP + r) * cD + d];
  }
  for (int s = 0; s < cS; ++s) {
    const float y = srwm_step(xp[s], wy, wq, wk, wbr);
    const float s1 = row_sum16(y);
    const float s2 = row_sum16(y * y);
    const float m = s1 * 0.0625f;
    const float var = s2 * 0.0625f - m * m;
    h[((size_t)(s * cB + b) * cP + r) * cD + d] = (y - m) * rsqrtf(var + LEPS) * gg + bb;
  }
}

// ---------------- token mixer: LN(D) then FFN over patch axis --------------
__global__ __launch_bounds__(256) void k_tok_mixer(
    float* __restrict__ h, const float* __restrict__ g, const float* __restrict__ bta,
    const float* __restrict__ W1, const float* __restrict__ b1,
    const float* __restrict__ W2, const float* __restrict__ b2) {
  const int sb = blockIdx.x;
  const int t = threadIdx.x;
  __shared__ float tile[16][256];
  __shared__ float W1s[16 * 64], W2s[64 * 16];
  __shared__ float mean_[16], rstd_[16];
  __shared__ float red[16][17], red2[16][17];
  const size_t base = (size_t)sb * cP * cD;
#pragma unroll
  for (int p = 0; p < 16; ++p) tile[p][t] = h[base + p * 256 + t];
  W1s[t] = W1[t]; W1s[t + 256] = W1[t + 256]; W1s[t + 512] = W1[t + 512]; W1s[t + 768] = W1[t + 768];
  W2s[t] = W2[t]; W2s[t + 256] = W2[t + 256]; W2s[t + 512] = W2[t + 512]; W2s[t + 768] = W2[t + 768];
  __syncthreads();
  const int p = t >> 4, l = t & 15;
  float ps = 0.f, ps2 = 0.f;
#pragma unroll
  for (int k = 0; k < 16; ++k) { const float v = tile[p][l + 16 * k]; ps += v; ps2 += v * v; }
  red[p][l] = ps; red2[p][l] = ps2;
  __syncthreads();
  if (t < 16) {
    float sm = 0.f, s2 = 0.f;
#pragma unroll
    for (int k = 0; k < 16; ++k) { sm += red[t][k]; s2 += red2[t][k]; }
    const float m = sm * (1.f / 256.f);
    mean_[t] = m;
    rstd_[t] = rsqrtf(s2 * (1.f / 256.f) - m * m + LEPS);
  }
  __syncthreads();
  const float gd = g[t], bd = bta[t];
  float v[16], out[16];
#pragma unroll
  for (int pp = 0; pp < 16; ++pp) {
    v[pp] = (tile[pp][t] - mean_[pp]) * rstd_[pp] * gd + bd;
    out[pp] = b2[pp];
  }
  for (int e = 0; e < 64; ++e) {
    float acc = b1[e];
#pragma unroll
    for (int pp = 0; pp < 16; ++pp) acc += v[pp] * W1s[pp * 64 + e];
    const float ge = gelu_t(acc);
#pragma unroll
    for (int pp = 0; pp < 16; ++pp) out[pp] += ge * W2s[e * 16 + pp];
  }
#pragma unroll
  for (int pp = 0; pp < 16; ++pp) h[base + pp * 256 + t] = tile[pp][t] + out[pp];
}

// --------- channel SRWM scan: 256 blocks x 128 threads (8 heads each) ------
__global__ __launch_bounds__(128) void k_ch_scan(
    const float* __restrict__ h, float* __restrict__ y2,
    const float* __restrict__ Wy0, const float* __restrict__ Wq0,
    const float* __restrict__ Wk0, const float* __restrict__ wb0) {
  const int t  = threadIdx.x;
  const int hg = blockIdx.x & 1;
  const int bp = blockIdx.x >> 1;
  const int hh = (hg << 3) + (t >> 4);
  const int r  = t & 15;
  const int d  = (hg << 7) + t;
  float wy[16], wq[16], wk[16], wbr[16];
#pragma unroll
  for (int j = 0; j < 16; ++j) {
    wy[j]  = Wy0[(hh * 16 + r) * 16 + j];
    wq[j]  = Wq0[(hh * 16 + r) * 16 + j];
    wk[j]  = Wk0[(hh * 16 + r) * 16 + j];
    wbr[j] = wb0[(hh * 4 + (r & 3)) * 16 + j];
  }
  float xp[16];
#pragma unroll
  for (int s = 0; s < 16; ++s)
    xp[s] = h[(size_t)(s * cB * cP + bp) * cD + d];
  for (int s = 0; s < cS; ++s)
    y2[(size_t)(s * cB * cP + bp) * cD + d] = srwm_step(xp[s], wy, wq, wk, wbr);
}

// --------- channel LN1 + mixer (DOFLN=1: + final LN + patch-mean) ----------
// DOFLN=0: 256 blocks x 8 rows (layer 0). DOFLN=1: 128 blocks x 16 rows =
// one (s,b) each; final h kept in LDS, fln+mean emitted to gbuf directly.
template<int DOFLN>
__global__ __launch_bounds__(256) void k_ch_ln_mix(
    const float* __restrict__ y2, float* __restrict__ h,
    const float* __restrict__ lng, const float* __restrict__ lnb,
    const float* __restrict__ mg, const float* __restrict__ mb,
    const float* __restrict__ W1, const float* __restrict__ b1,
    const float* __restrict__ W2, const float* __restrict__ b2,
    const float* __restrict__ flng, const float* __restrict__ flnb,
    float* __restrict__ gbuf) {
  const int t = threadIdx.x;
  const int row0 = blockIdx.x * (DOFLN ? 16 : 8);
  __shared__ float yv[8][256];
  __shared__ float lnv[8][256];
  __shared__ float hid[8][128];
  __shared__ float hstore[DOFLN ? 16 : 1][256];
  __shared__ float mean_[16], rstd_[16];
  const int r32 = t >> 5, l = t & 31;
  const float4 eg0 = ((const float4*)lng)[l * 2];
  const float4 eg1 = ((const float4*)lng)[l * 2 + 1];
  const float4 eb0 = ((const float4*)lnb)[l * 2];
  const float4 eb1 = ((const float4*)lnb)[l * 2 + 1];
  const float4 mg0 = ((const float4*)mg)[l * 2];
  const float4 mg1 = ((const float4*)mg)[l * 2 + 1];
  const float4 mb0 = ((const float4*)mb)[l * 2];
  const float4 mb1 = ((const float4*)mb)[l * 2 + 1];
  for (int grp = 0; grp < (DOFLN ? 2 : 1); ++grp) {
    const int gr0 = row0 + grp * 8;
    const float4* yp4 = (const float4*)(y2 + (size_t)gr0 * cD);
    ((float4*)yv)[t]       = yp4[t];
    ((float4*)yv)[t + 256] = yp4[t + 256];
    __syncthreads();
    const float4 y0 = ((const float4*)yv[r32])[l * 2];
    const float4 y1 = ((const float4*)yv[r32])[l * 2 + 1];
    float s1 = y0.x + y0.y + y0.z + y0.w + y1.x + y1.y + y1.z + y1.w;
    float s2 = y0.x * y0.x + y0.y * y0.y + y0.z * y0.z + y0.w * y0.w +
               y1.x * y1.x + y1.y * y1.y + y1.z * y1.z + y1.w * y1.w;
#pragma unroll
    for (int o = 1; o < 32; o <<= 1) {
      s1 += __shfl_xor(s1, o, 32);
      s2 += __shfl_xor(s2, o, 32);
    }
    const float m1 = s1 * (1.f / 256.f);
    const float rst1 = rsqrtf(s2 * (1.f / 256.f) - m1 * m1 + LEPS);
    float4 a0, a1;   // SRWM output after its LN (the mixer's residual input)
    a0.x = (y0.x - m1) * rst1 * eg0.x + eb0.x; a0.y = (y0.y - m1) * rst1 * eg0.y + eb0.y;
    a0.z = (y0.z - m1) * rst1 * eg0.z + eb0.z; a0.w = (y0.w - m1) * rst1 * eg0.w + eb0.w;
    a1.x = (y1.x - m1) * rst1 * eg1.x + eb1.x; a1.y = (y1.y - m1) * rst1 * eg1.y + eb1.y;
    a1.z = (y1.z - m1) * rst1 * eg1.z + eb1.z; a1.w = (y1.w - m1) * rst1 * eg1.w + eb1.w;
    float u1 = a0.x + a0.y + a0.z + a0.w + a1.x + a1.y + a1.z + a1.w;
    float u2 = a0.x * a0.x + a0.y * a0.y + a0.z * a0.z + a0.w * a0.w +
               a1.x * a1.x + a1.y * a1.y + a1.z * a1.z + a1.w * a1.w;
#pragma unroll
    for (int o = 1; o < 32; o <<= 1) {
      u1 += __shfl_xor(u1, o, 32);
      u2 += __shfl_xor(u2, o, 32);
    }
    const float m2 = u1 * (1.f / 256.f);
    const float rst2 = rsqrtf(u2 * (1.f / 256.f) - m2 * m2 + LEPS);
    float4 L0, L1;
    L0.x = (a0.x - m2) * rst2 * mg0.x + mb0.x; L0.y = (a0.y - m2) * rst2 * mg0.y + mb0.y;
    L0.z = (a0.z - m2) * rst2 * mg0.z + mb0.z; L0.w = (a0.w - m2) * rst2 * mg0.w + mb0.w;
    L1.x = (a1.x - m2) * rst2 * mg1.x + mb1.x; L1.y = (a1.y - m2) * rst2 * mg1.y + mb1.y;
    L1.z = (a1.z - m2) * rst2 * mg1.z + mb1.z; L1.w = (a1.w - m2) * rst2 * mg1.w + mb1.w;
    ((float4*)lnv[r32])[l * 2]     = L0;
    ((float4*)lnv[r32])[l * 2 + 1] = L1;
    __syncthreads();
    {
      const float4* W1f = (const float4*)W1;
      float4 acc = ((const float4*)b1)[l];
      for (int j = 0; j < 256; ++j) {
        const float xj = lnv[r32][j];
        const float4 wv = W1f[j * 32 + l];
        acc.x += xj * wv.x; acc.y += xj * wv.y; acc.z += xj * wv.z; acc.w += xj * wv.w;
      }
      float4 hv;
      hv.x = gelu_t(acc.x); hv.y = gelu_t(acc.y);
      hv.z = gelu_t(acc.z); hv.w = gelu_t(acc.w);
      ((float4*)hid[r32])[l] = hv;
    }
    __syncthreads();
    {
      const float4* W2f = (const float4*)W2;
      float4 o0 = ((const float4*)b2)[l * 2];
      float4 o1 = ((const float4*)b2)[l * 2 + 1];
      for (int e = 0; e < 128; ++e) {
        const float xh = hid[r32][e];
        const float4 w0 = W2f[e * 64 + l * 2];
        const float4 w1 = W2f[e * 64 + l * 2 + 1];
        o0.x += xh * w0.x; o0.y += xh * w0.y; o0.z += xh * w0.z; o0.w += xh * w0.w;
        o1.x += xh * w1.x; o1.y += xh * w1.y; o1.z += xh * w1.z; o1.w += xh * w1.w;
      }
      o0.x += a0.x; o0.y += a0.y; o0.z += a0.z; o0.w += a0.w;
      o1.x += a1.x; o1.y += a1.y; o1.z += a1.z; o1.w += a1.w;
      if constexpr (DOFLN) {
        ((float4*)hstore[grp * 8 + r32])[l * 2]     = o0;
        ((float4*)hstore[grp * 8 + r32])[l * 2 + 1] = o1;
      } else {
        float4* op = (float4*)(h + ((size_t)gr0 + r32) * cD);
        op[l * 2]     = o0;
        op[l * 2 + 1] = o1;
      }
    }
    __syncthreads();
  }
  if constexpr (DOFLN) {
    // per-row LN stats: 8 groups of 32 lanes x 2 rows each
    for (int rr = r32; rr < 16; rr += 8) {
      const float4 v0 = ((const float4*)hstore[rr])[l * 2];
      const float4 v1 = ((const float4*)hstore[rr])[l * 2 + 1];
      float s1 = v0.x + v0.y + v0.z + v0.w + v1.x + v1.y + v1.z + v1.w;
      float s2 = v0.x * v0.x + v0.y * v0.y + v0.z * v0.z + v0.w * v0.w +
                 v1.x * v1.x + v1.y * v1.y + v1.z * v1.z + v1.w * v1.w;
#pragma unroll
      for (int o = 1; o < 32; o <<= 1) {
        s1 += __shfl_xor(s1, o, 32);
        s2 += __shfl_xor(s2, o, 32);
      }
      if (l == 0) {
        const float m = s1 * (1.f / 256.f);
        mean_[rr] = m;
        rstd_[rr] = rsqrtf(s2 * (1.f / 256.f) - m * m + LEPS);
      }
    }
    __syncthreads();
    float acc = 0.f;
#pragma unroll
    for (int p = 0; p < 16; ++p)
      acc += (hstore[p][t] - mean_[p]) * rstd_[p];
    gbuf[(size_t)blockIdx.x * cD + t] = flng[t] * acc * (1.f / 16.f) + flnb[t];
  }
}

// -------- output SRWM: barrier-free scan + batched LN/projection ----------
__global__ __launch_bounds__(256, 1) void k_out_srwm(
    const float* __restrict__ gin, float* __restrict__ outp,
    const float* __restrict__ Wy0, const float* __restrict__ Wq0,
    const float* __restrict__ Wk0, const float* __restrict__ wb0,
    const float* __restrict__ lng, const float* __restrict__ lnb,
    const float* __restrict__ outW, const float* __restrict__ outb) {
  const int t = threadIdx.x;
  const int lane = t & 63;
  const int w = t >> 6;
  const int hh = t >> 4, r = t & 15;
  const int b = blockIdx.x;
  __shared__ float ymat[16][256];
  __shared__ float gwm[cNC][256];
  __shared__ float GBp[4][10];
  __shared__ float GBs[10];
  float wy[16], wq[16], wk[16], wbr[16];
#pragma unroll
  for (int j = 0; j < 16; ++j) {
    wy[j]  = Wy0[(hh * 16 + r) * 16 + j];
    wq[j]  = Wq0[(hh * 16 + r) * 16 + j];
    wk[j]  = Wk0[(hh * 16 + r) * 16 + j];
    wbr[j] = wb0[(hh * 4 + (r & 3)) * 16 + j];
  }
  {
    const float gg = lng[t], bbl = lnb[t];
    float pg[cNC], pbv[cNC];
#pragma unroll
    for (int c = 0; c < cNC; ++c) {
      const float wv = outW[(size_t)t * cNC + c];
      const float gwv = gg * wv;
      gwm[c][t] = gwv;
      pg[c] = wave_sum64(gwv);
      pbv[c] = wave_sum64(bbl * wv);
    }
    if (lane == 0) {
#pragma unroll
      for (int c = 0; c < cNC; ++c) { GBp[w][c] = pg[c]; GBp[w][5 + c] = pbv[c]; }
    }
    __syncthreads();
    if (t < 10) GBs[t] = GBp[0][t] + GBp[1][t] + GBp[2][t] + GBp[3][t];
    __syncthreads();
  }
  float xp[16];
#pragma unroll
  for (int s = 0; s < 16; ++s) xp[s] = gin[(size_t)(s * cB + b) * cD + t];
  for (int s = 0; s < cS; ++s)
    ymat[s][t] = srwm_step(xp[s], wy, wq, wk, wbr);
  __syncthreads();
  for (int k2 = 0; k2 < 4; ++k2) {
    const int sidx = w * 4 + k2;
    const float4 y4 = ((const float4*)ymat[sidx])[lane];
    const float s1 = wave_sum64(y4.x + y4.y + y4.z + y4.w);
    const float s2 = wave_sum64(y4.x * y4.x + y4.y * y4.y + y4.z * y4.z + y4.w * y4.w);
    float S[cNC];
#pragma unroll
    for (int c = 0; c < cNC; ++c) {
      const float4 g4 = ((const float4*)gwm[c])[lane];
      S[c] = wave_sum64(y4.x * g4.x + y4.y * g4.y + y4.z * g4.z + y4.w * g4.w);
    }
    if (lane == 0) {
      const float m = s1 * (1.f / 256.f);
      const float var = s2 * (1.f / 256.f) - m * m;
      const float rst = rsqrtf(var + LEPS);
#pragma unroll
      for (int c = 0; c < cNC; ++c) {
        outp[(size_t)(sidx * cB + b) * cNC + c] =
            outb[c] + rst * S[c] - rst * m * GBs[c] + GBs[5 + c];
      }
    }
  }
}

extern "C" void kernel_launch(void* const* d_in, const int* in_sizes, int n_in,
                              void* d_out, int out_size, void* d_ws, size_t ws_size,
                              hipStream_t stream) {
  const float* x     = (const float*)d_in[0];
  const int*   fb    = (const int*)d_in[1];
  const float* inW   = (const float*)d_in[2];
  const float* inb   = (const float*)d_in[3];
  const float* tkWy  = (const float*)d_in[4];
  const float* tkWq  = (const float*)d_in[5];
  const float* tkWk  = (const float*)d_in[6];
  const float* tkwb  = (const float*)d_in[7];
  const float* tklng = (const float*)d_in[8];
  const float* tklnb = (const float*)d_in[9];
  const float* tkmg  = (const float*)d_in[10];
  const float* tkmb  = (const float*)d_in[11];
  const float* tkmW1 = (const float*)d_in[12];
  const float* tkmb1 = (const float*)d_in[13];
  const float* tkmW2 = (const float*)d_in[14];
  const float* tkmb2 = (const float*)d_in[15];
  const float* chWy  = (const float*)d_in[16];
  const float* chWq  = (const float*)d_in[17];
  const float* chWk  = (const float*)d_in[18];
  const float* chwb  = (const float*)d_in[19];
  const float* chlng = (const float*)d_in[20];
  const float* chlnb = (const float*)d_in[21];
  const float* chmg  = (const float*)d_in[22];
  const float* chmb  = (const float*)d_in[23];
  const float* chmW1 = (const float*)d_in[24];
  const float* chmb1 = (const float*)d_in[25];
  const float* chmW2 = (const float*)d_in[26];
  const float* chmb2 = (const float*)d_in[27];
  const float* flng  = (const float*)d_in[28];
  const float* flnb  = (const float*)d_in[29];
  const float* oWy   = (const float*)d_in[30];
  const float* oWq   = (const float*)d_in[31];
  const float* oWk   = (const float*)d_in[32];
  const float* owb   = (const float*)d_in[33];
  const float* olng  = (const float*)d_in[34];
  const float* olnb  = (const float*)d_in[35];
  const float* outW  = (const float*)d_in[36];
  const float* outb  = (const float*)d_in[37];

  float* h    = (float*)d_ws;                               // (S,B,P,D) 2 MB
  float* gbuf = h + (size_t)cS * cB * cP * cD;              // (S,B,D)
  float* y2   = gbuf + (size_t)cS * cB * cD;                // (S,B,P,D) 2 MB scratch
  float* outp = (float*)d_out;                              // (S,B,NC)

  for (int i = 0; i < 2; ++i) {
    k_tok_srwm<<<dim3(256), dim3(128), 0, stream>>>(
        h, tkWy + i * 256, tkWq + i * 256, tkWk + i * 256, tkwb + i * 64,
        tklng + i * 16, tklnb + i * 16,
        (i == 0) ? 1 : 0, x, fb, inW, inb);
    k_tok_mixer<<<dim3(cS * cB), dim3(256), 0, stream>>>(
        h, tkmg + i * 256, tkmb + i * 256, tkmW1 + i * 1024, tkmb1 + i * 64,
        tkmW2 + i * 1024, tkmb2 + i * 16);
    k_ch_scan<<<dim3(cB * cP * 2), dim3(128), 0, stream>>>(
        h, y2, chWy + i * 4096, chWq + i * 4096, chWk + i * 4096, chwb + i * 1024);
    if (i == 0) {
      k_ch_ln_mix<0><<<dim3(cS * cB * cP / 8), dim3(256), 0, stream>>>(
          y2, h, chlng + i * 256, chlnb + i * 256,
          chmg + i * 256, chmb + i * 256, chmW1 + i * 32768, chmb1 + i * 128,
          chmW2 + i * 32768, chmb2 + i * 256, flng, flnb, gbuf);
    } else {
      k_ch_ln_mix<1><<<dim3(cS * cB), dim3(256), 0, stream>>>(
          y2, h, chlng + i * 256, chlnb + i * 256,
          chmg + i * 256, chmb + i * 256, chmW1 + i * 32768, chmb1 + i * 128,
          chmW2 + i * 32768, chmb2 + i * 256, flng, flnb, gbuf);
    }
  }
  k_out_srwm<<<dim3(cB), dim3(256), 0, stream>>>(
      gbuf, outp, oWy, oWq, oWk, owb, olng, olnb, outW, outb);
}

// Round 15
// 312.560 us; speedup vs baseline: 1.1083x; 1.1083x over previous
//
#include <hip/hip_runtime.h>
#include <math.h>

// Problem constants (from reference)
constexpr int cS  = 16;   // sequence
constexpr int cB  = 8;    // batch
constexpr int cNC = 5;    // classes
constexpr int cD  = 256;  // hidden
constexpr int cP  = 16;   // patches
constexpr int cPD = 49;   // patch dim
#define LEPS 1e-5f

__device__ __forceinline__ float frcp(float x) { return __builtin_amdgcn_rcpf(x); }
__device__ __forceinline__ float sigm(float x) { return frcp(1.0f + __expf(-x)); }
__device__ __forceinline__ float gelu_t(float x) {
  const float z = 1.5957691216057308f * (x + 0.044715f * x * x * x);
  return x * frcp(1.0f + __expf(-z));
}

// ---- DPP 16-lane reductions (reductions only — matvec broadcasts stay on
// ---- the DS pipe via __shfl, which overlaps with VALU; R12 proved moving
// ---- them to DPP/VALU serializes the pipes and loses).
template<int CTRL>
__device__ __forceinline__ float dpp_mov(float v) {
  return __int_as_float(__builtin_amdgcn_update_dpp(
      0, __float_as_int(v), CTRL, 0xF, 0xF, true));
}
__device__ __forceinline__ float row_sum16(float v) {
  v += dpp_mov<0xB1>(v);   // quad_perm [1,0,3,2]
  v += dpp_mov<0x4E>(v);   // quad_perm [2,3,0,1]
  v += dpp_mov<0x124>(v);  // row_ror:4
  v += dpp_mov<0x128>(v);  // row_ror:8
  return v;
}
__device__ __forceinline__ float wave_sum64(float v) {
  v = row_sum16(v);
  v += __shfl_xor(v, 16, 64);
  v += __shfl_xor(v, 32, 64);
  return v;
}

// ---- SRWM step (shuffle/bpermute broadcasts, deferred softmax normalize)
__device__ __forceinline__ float srwm_step(
    float xv, float (&wy)[16], float (&wq)[16], float (&wk)[16], float (&wbr)[16]) {
  float y = 0.f, q = 0.f, k = 0.f, bt = 0.f;
#pragma unroll
  for (int j = 0; j < 16; ++j) {
    const float xj = __shfl(xv, j, 16);
    y += wy[j] * xj; q += wq[j] * xj; k += wk[j] * xj; bt += wbr[j] * xj;
  }
  const float bsig = sigm(bt);
  const float eq = __expf(q), ek = __expf(k);
  float ay = 0.f, vyk = 0.f, vqq = 0.f, vqk = 0.f, vkq = 0.f, vkk = 0.f, vbq = 0.f, vbk = 0.f;
  float ksj[16];
#pragma unroll
  for (int j = 0; j < 16; ++j) {
    const float qj = __shfl(eq, j, 16);
    const float kj = __shfl(ek, j, 16);
    ksj[j] = kj;
    ay  += wy[j]  * qj; vyk += wy[j]  * kj;
    vqq += wq[j]  * qj; vqk += wq[j]  * kj;
    vkq += wk[j]  * qj; vkk += wk[j]  * kj;
    vbq += wbr[j] * qj; vbk += wbr[j] * kj;
  }
  const float rq = frcp(row_sum16(eq));
  const float rk = frcp(row_sum16(ek));
  const float ea = __expf(ay * rq);
  const float vyq = ea * frcp(row_sum16(ea));
  const float b0  = __shfl(bsig, 0, 16);
  const float b1v = __shfl(bsig, 1, 16);
  const float b2v = __shfl(bsig, 2, 16);
  const float b3v = __shfl(bsig, 3, 16);
  const float cy = b0  * (vyq      - vyk * rk) * rk;
  const float cq = b1v * (vqq * rq - vqk * rk) * rk;
  const float ck = b2v * (vkq * rq - vkk * rk) * rk;
  const float cb = b3v * (vbq * rq - vbk * rk) * rk;
#pragma unroll
  for (int j = 0; j < 16; ++j) {
    wy[j] += cy * ksj[j]; wq[j] += cq * ksj[j]; wk[j] += ck * ksj[j]; wbr[j] += cb * ksj[j];
  }
  return y;
}

// ---------------- embed: patchify + one-hot concat + linear ----------------
__global__ __launch_bounds__(256) void k_embed(const float* __restrict__ x,
                                               const int* __restrict__ fb,
                                               const float* __restrict__ inW,
                                               const float* __restrict__ inb,
                                               float* __restrict__ h) {
  const int blk = blockIdx.x;
  const int p  = blk & 15;
  const int sb = blk >> 4;
  const int ph = p >> 2, pw = p & 3;
  __shared__ float sx[cPD];
  const int t = threadIdx.x;
  if (t < cPD) {
    const int p1 = t / 7, p2 = t % 7;
    sx[t] = x[(size_t)sb * 784 + (ph * 7 + p1) * 28 + (pw * 7 + p2)];
  }
  __syncthreads();
  const int cls = fb[sb];
  float acc = inb[t] + inW[(size_t)(cPD + cls) * cD + t];
#pragma unroll
  for (int j = 0; j < cPD; ++j) acc += sx[j] * inW[(size_t)j * cD + t];
  h[((size_t)sb * cP + p) * cD + t] = acc;
}

// --------- token SRWM: 256 blocks x 128 threads (all 256 CUs) --------------
__global__ __launch_bounds__(128) void k_tok_srwm(
    float* __restrict__ h, const float* __restrict__ Wy0, const float* __restrict__ Wq0,
    const float* __restrict__ Wk0, const float* __restrict__ wb0,
    const float* __restrict__ lng, const float* __restrict__ lnb) {
  const int t    = threadIdx.x;
  const int lane = t & 63;
  const int w    = t >> 6;              // 0..1
  const int r    = lane & 15;
  const int li   = lane >> 4;
  const int b    = blockIdx.x >> 5;     // 8 b x 32 dgroups
  const int d    = ((blockIdx.x & 31) << 3) + (w << 2) + li;
  float wy[16], wq[16], wk[16], wbr[16];
#pragma unroll
  for (int j = 0; j < 16; ++j) {
    wy[j]  = Wy0[r * 16 + j];
    wq[j]  = Wq0[r * 16 + j];
    wk[j]  = Wk0[r * 16 + j];
    wbr[j] = wb0[(r & 3) * 16 + j];
  }
  const float gg = lng[r], bb = lnb[r];
  float xp[16];
#pragma unroll
  for (int s = 0; s < 16; ++s)
    xp[s] = h[((size_t)(s * cB + b) * cP + r) * cD + d];
  for (int s = 0; s < cS; ++s) {
    const float y = srwm_step(xp[s], wy, wq, wk, wbr);
    const float s1 = row_sum16(y);
    const float s2 = row_sum16(y * y);
    const float m = s1 * 0.0625f;
    const float var = s2 * 0.0625f - m * m;
    h[((size_t)(s * cB + b) * cP + r) * cD + d] = (y - m) * rsqrtf(var + LEPS) * gg + bb;
  }
}

// ---------------- token mixer: LN(D) then FFN over patch axis --------------
__global__ __launch_bounds__(256) void k_tok_mixer(
    float* __restrict__ h, const float* __restrict__ g, const float* __restrict__ bta,
    const float* __restrict__ W1, const float* __restrict__ b1,
    const float* __restrict__ W2, const float* __restrict__ b2) {
  const int sb = blockIdx.x;
  const int t = threadIdx.x;
  __shared__ float tile[16][256];
  __shared__ float W1s[16 * 64], W2s[64 * 16];
  __shared__ float mean_[16], rstd_[16];
  __shared__ float red[16][17], red2[16][17];
  const size_t base = (size_t)sb * cP * cD;
#pragma unroll
  for (int p = 0; p < 16; ++p) tile[p][t] = h[base + p * 256 + t];
  W1s[t] = W1[t]; W1s[t + 256] = W1[t + 256]; W1s[t + 512] = W1[t + 512]; W1s[t + 768] = W1[t + 768];
  W2s[t] = W2[t]; W2s[t + 256] = W2[t + 256]; W2s[t + 512] = W2[t + 512]; W2s[t + 768] = W2[t + 768];
  __syncthreads();
  const int p = t >> 4, l = t & 15;
  float ps = 0.f, ps2 = 0.f;
#pragma unroll
  for (int k = 0; k < 16; ++k) { const float v = tile[p][l + 16 * k]; ps += v; ps2 += v * v; }
  red[p][l] = ps; red2[p][l] = ps2;
  __syncthreads();
  if (t < 16) {
    float sm = 0.f, s2 = 0.f;
#pragma unroll
    for (int k = 0; k < 16; ++k) { sm += red[t][k]; s2 += red2[t][k]; }
    const float m = sm * (1.f / 256.f);
    mean_[t] = m;
    rstd_[t] = rsqrtf(s2 * (1.f / 256.f) - m * m + LEPS);
  }
  __syncthreads();
  const float gd = g[t], bd = bta[t];
  float v[16], out[16];
#pragma unroll
  for (int pp = 0; pp < 16; ++pp) {
    v[pp] = (tile[pp][t] - mean_[pp]) * rstd_[pp] * gd + bd;
    out[pp] = b2[pp];
  }
  for (int e = 0; e < 64; ++e) {
    float acc = b1[e];
#pragma unroll
    for (int pp = 0; pp < 16; ++pp) acc += v[pp] * W1s[pp * 64 + e];
    const float ge = gelu_t(acc);
#pragma unroll
    for (int pp = 0; pp < 16; ++pp) out[pp] += ge * W2s[e * 16 + pp];
  }
#pragma unroll
  for (int pp = 0; pp < 16; ++pp) h[base + pp * 256 + t] = tile[pp][t] + out[pp];
}

// --------- channel SRWM scan: 256 blocks x 128 threads (8 heads each) ------
// Heads are independent in the scan (LN deferred); raw y -> y2 scratch.
__global__ __launch_bounds__(128) void k_ch_scan(
    const float* __restrict__ h, float* __restrict__ y2,
    const float* __restrict__ Wy0, const float* __restrict__ Wq0,
    const float* __restrict__ Wk0, const float* __restrict__ wb0) {
  const int t  = threadIdx.x;
  const int hg = blockIdx.x & 1;        // head group (0: heads 0-7, 1: 8-15)
  const int bp = blockIdx.x >> 1;       // (b,p) instance
  const int hh = (hg << 3) + (t >> 4);  // global head
  const int r  = t & 15;
  const int d  = (hg << 7) + t;         // = hh*16 + r
  float wy[16], wq[16], wk[16], wbr[16];
#pragma unroll
  for (int j = 0; j < 16; ++j) {
    wy[j]  = Wy0[(hh * 16 + r) * 16 + j];
    wq[j]  = Wq0[(hh * 16 + r) * 16 + j];
    wk[j]  = Wk0[(hh * 16 + r) * 16 + j];
    wbr[j] = wb0[(hh * 4 + (r & 3)) * 16 + j];
  }
  float xp[16];
#pragma unroll
  for (int s = 0; s < 16; ++s)
    xp[s] = h[(size_t)(s * cB * cP + bp) * cD + d];
  for (int s = 0; s < cS; ++s)
    y2[(size_t)(s * cB * cP + bp) * cD + d] = srwm_step(xp[s], wy, wq, wk, wbr);
}

// --------- channel LN1 + mixer: 256 blocks x 256 threads, 8 rows each ------
__global__ __launch_bounds__(256) void k_ch_ln_mix(
    const float* __restrict__ y2, float* __restrict__ h,
    const float* __restrict__ lng, const float* __restrict__ lnb,
    const float* __restrict__ mg, const float* __restrict__ mb,
    const float* __restrict__ W1, const float* __restrict__ b1,
    const float* __restrict__ W2, const float* __restrict__ b2) {
  const int t = threadIdx.x;
  const int row0 = blockIdx.x * 8;
  __shared__ float yv[8][256];
  __shared__ float lnv[8][256];
  __shared__ float hid[8][128];
  // cooperative load of 8 consecutive rows (2048 consecutive floats)
  const float4* yp4 = (const float4*)(y2 + (size_t)row0 * cD);
  ((float4*)yv)[t]       = yp4[t];
  ((float4*)yv)[t + 256] = yp4[t + 256];
  __syncthreads();
  const int r32 = t >> 5, l = t & 31;
  const float4 eg0 = ((const float4*)lng)[l * 2];
  const float4 eg1 = ((const float4*)lng)[l * 2 + 1];
  const float4 eb0 = ((const float4*)lnb)[l * 2];
  const float4 eb1 = ((const float4*)lnb)[l * 2 + 1];
  const float4 mg0 = ((const float4*)mg)[l * 2];
  const float4 mg1 = ((const float4*)mg)[l * 2 + 1];
  const float4 mb0 = ((const float4*)mb)[l * 2];
  const float4 mb1 = ((const float4*)mb)[l * 2 + 1];
  const float4 y0 = ((const float4*)yv[r32])[l * 2];
  const float4 y1 = ((const float4*)yv[r32])[l * 2 + 1];
  float s1 = y0.x + y0.y + y0.z + y0.w + y1.x + y1.y + y1.z + y1.w;
  float s2 = y0.x * y0.x + y0.y * y0.y + y0.z * y0.z + y0.w * y0.w +
             y1.x * y1.x + y1.y * y1.y + y1.z * y1.z + y1.w * y1.w;
#pragma unroll
  for (int o = 1; o < 32; o <<= 1) {
    s1 += __shfl_xor(s1, o, 32);
    s2 += __shfl_xor(s2, o, 32);
  }
  const float m1 = s1 * (1.f / 256.f);
  const float rst1 = rsqrtf(s2 * (1.f / 256.f) - m1 * m1 + LEPS);
  float4 a0, a1;   // SRWM output after its LN (the mixer's residual input)
  a0.x = (y0.x - m1) * rst1 * eg0.x + eb0.x; a0.y = (y0.y - m1) * rst1 * eg0.y + eb0.y;
  a0.z = (y0.z - m1) * rst1 * eg0.z + eb0.z; a0.w = (y0.w - m1) * rst1 * eg0.w + eb0.w;
  a1.x = (y1.x - m1) * rst1 * eg1.x + eb1.x; a1.y = (y1.y - m1) * rst1 * eg1.y + eb1.y;
  a1.z = (y1.z - m1) * rst1 * eg1.z + eb1.z; a1.w = (y1.w - m1) * rst1 * eg1.w + eb1.w;
  float u1 = a0.x + a0.y + a0.z + a0.w + a1.x + a1.y + a1.z + a1.w;
  float u2 = a0.x * a0.x + a0.y * a0.y + a0.z * a0.z + a0.w * a0.w +
             a1.x * a1.x + a1.y * a1.y + a1.z * a1.z + a1.w * a1.w;
#pragma unroll
  for (int o = 1; o < 32; o <<= 1) {
    u1 += __shfl_xor(u1, o, 32);
    u2 += __shfl_xor(u2, o, 32);
  }
  const float m2 = u1 * (1.f / 256.f);
  const float rst2 = rsqrtf(u2 * (1.f / 256.f) - m2 * m2 + LEPS);
  float4 L0, L1;
  L0.x = (a0.x - m2) * rst2 * mg0.x + mb0.x; L0.y = (a0.y - m2) * rst2 * mg0.y + mb0.y;
  L0.z = (a0.z - m2) * rst2 * mg0.z + mb0.z; L0.w = (a0.w - m2) * rst2 * mg0.w + mb0.w;
  L1.x = (a1.x - m2) * rst2 * mg1.x + mb1.x; L1.y = (a1.y - m2) * rst2 * mg1.y + mb1.y;
  L1.z = (a1.z - m2) * rst2 * mg1.z + mb1.z; L1.w = (a1.w - m2) * rst2 * mg1.w + mb1.w;
  ((float4*)lnv[r32])[l * 2]     = L0;
  ((float4*)lnv[r32])[l * 2 + 1] = L1;
  __syncthreads();
  {
    const float4* W1f = (const float4*)W1;
    float4 acc = ((const float4*)b1)[l];
    for (int j = 0; j < 256; ++j) {
      const float xj = lnv[r32][j];
      const float4 wv = W1f[j * 32 + l];
      acc.x += xj * wv.x; acc.y += xj * wv.y; acc.z += xj * wv.z; acc.w += xj * wv.w;
    }
    float4 hv;
    hv.x = gelu_t(acc.x); hv.y = gelu_t(acc.y);
    hv.z = gelu_t(acc.z); hv.w = gelu_t(acc.w);
    ((float4*)hid[r32])[l] = hv;
  }
  __syncthreads();
  {
    const float4* W2f = (const float4*)W2;
    float4 o0 = ((const float4*)b2)[l * 2];
    float4 o1 = ((const float4*)b2)[l * 2 + 1];
    for (int e = 0; e < 128; ++e) {
      const float xh = hid[r32][e];
      const float4 w0 = W2f[e * 64 + l * 2];
      const float4 w1 = W2f[e * 64 + l * 2 + 1];
      o0.x += xh * w0.x; o0.y += xh * w0.y; o0.z += xh * w0.z; o0.w += xh * w0.w;
      o1.x += xh * w1.x; o1.y += xh * w1.y; o1.z += xh * w1.z; o1.w += xh * w1.w;
    }
    o0.x += a0.x; o0.y += a0.y; o0.z += a0.z; o0.w += a0.w;
    o1.x += a1.x; o1.y += a1.y; o1.z += a1.z; o1.w += a1.w;
    float4* op = (float4*)(h + ((size_t)row0 + r32) * cD);
    op[l * 2]     = o0;
    op[l * 2 + 1] = o1;
  }
}

// ---------------- final LN + mean over patches -----------------------------
__global__ __launch_bounds__(256) void k_fln_mean(
    const float* __restrict__ h, const float* __restrict__ gg, const float* __restrict__ bbv,
    float* __restrict__ o) {
  const int sb = blockIdx.x;
  const int t = threadIdx.x;
  const int lane = t & 63, w = t >> 6;
  const float4 g4 = ((const float4*)gg)[lane];
  const float4 b4 = ((const float4*)bbv)[lane];
  float a0 = 0.f, a1 = 0.f, a2 = 0.f, a3 = 0.f;
  for (int pp = 0; pp < 4; ++pp) {
    const int p = w * 4 + pp;
    const float4 v4 = ((const float4*)(h + ((size_t)sb * cP + p) * cD))[lane];
    const float s1 = wave_sum64(v4.x + v4.y + v4.z + v4.w);
    const float s2 = wave_sum64(v4.x * v4.x + v4.y * v4.y + v4.z * v4.z + v4.w * v4.w);
    const float m = s1 * (1.f / 256.f);
    const float rst = rsqrtf(s2 * (1.f / 256.f) - m * m + LEPS);
    a0 += (v4.x - m) * rst * g4.x + b4.x;
    a1 += (v4.y - m) * rst * g4.y + b4.y;
    a2 += (v4.z - m) * rst * g4.z + b4.z;
    a3 += (v4.w - m) * rst * g4.w + b4.w;
  }
  __shared__ float sacc[4][256];
  float4* sp = (float4*)sacc[w];
  sp[lane] = make_float4(a0, a1, a2, a3);
  __syncthreads();
  o[(size_t)sb * cD + t] = (sacc[0][t] + sacc[1][t] + sacc[2][t] + sacc[3][t]) * (1.f / 16.f);
}

// -------- output SRWM: barrier-free scan + batched LN/projection ----------
__global__ __launch_bounds__(256, 1) void k_out_srwm(
    const float* __restrict__ gin, float* __restrict__ outp,
    const float* __restrict__ Wy0, const float* __restrict__ Wq0,
    const float* __restrict__ Wk0, const float* __restrict__ wb0,
    const float* __restrict__ lng, const float* __restrict__ lnb,
    const float* __restrict__ outW, const float* __restrict__ outb) {
  const int t = threadIdx.x;
  const int lane = t & 63;
  const int w = t >> 6;
  const int hh = t >> 4, r = t & 15;
  const int b = blockIdx.x;
  __shared__ float ymat[16][256];
  __shared__ float gwm[cNC][256];
  __shared__ float GBp[4][10];
  __shared__ float GBs[10];
  float wy[16], wq[16], wk[16], wbr[16];
#pragma unroll
  for (int j = 0; j < 16; ++j) {
    wy[j]  = Wy0[(hh * 16 + r) * 16 + j];
    wq[j]  = Wq0[(hh * 16 + r) * 16 + j];
    wk[j]  = Wk0[(hh * 16 + r) * 16 + j];
    wbr[j] = wb0[(hh * 4 + (r & 3)) * 16 + j];
  }
  {
    const float gg = lng[t], bbl = lnb[t];
    float pg[cNC], pbv[cNC];
#pragma unroll
    for (int c = 0; c < cNC; ++c) {
      const float wv = outW[(size_t)t * cNC + c];
      const float gwv = gg * wv;
      gwm[c][t] = gwv;
      pg[c] = wave_sum64(gwv);
      pbv[c] = wave_sum64(bbl * wv);
    }
    if (lane == 0) {
#pragma unroll
      for (int c = 0; c < cNC; ++c) { GBp[w][c] = pg[c]; GBp[w][5 + c] = pbv[c]; }
    }
    __syncthreads();
    if (t < 10) GBs[t] = GBp[0][t] + GBp[1][t] + GBp[2][t] + GBp[3][t];
    __syncthreads();
  }
  float xp[16];
#pragma unroll
  for (int s = 0; s < 16; ++s) xp[s] = gin[(size_t)(s * cB + b) * cD + t];
  for (int s = 0; s < cS; ++s)
    ymat[s][t] = srwm_step(xp[s], wy, wq, wk, wbr);
  __syncthreads();
  for (int k2 = 0; k2 < 4; ++k2) {
    const int sidx = w * 4 + k2;
    const float4 y4 = ((const float4*)ymat[sidx])[lane];
    const float s1 = wave_sum64(y4.x + y4.y + y4.z + y4.w);
    const float s2 = wave_sum64(y4.x * y4.x + y4.y * y4.y + y4.z * y4.z + y4.w * y4.w);
    float S[cNC];
#pragma unroll
    for (int c = 0; c < cNC; ++c) {
      const float4 g4 = ((const float4*)gwm[c])[lane];
      S[c] = wave_sum64(y4.x * g4.x + y4.y * g4.y + y4.z * g4.z + y4.w * g4.w);
    }
    if (lane == 0) {
      const float m = s1 * (1.f / 256.f);
      const float var = s2 * (1.f / 256.f) - m * m;
      const float rst = rsqrtf(var + LEPS);
#pragma unroll
      for (int c = 0; c < cNC; ++c) {
        outp[(size_t)(sidx * cB + b) * cNC + c] =
            outb[c] + rst * S[c] - rst * m * GBs[c] + GBs[5 + c];
      }
    }
  }
}

extern "C" void kernel_launch(void* const* d_in, const int* in_sizes, int n_in,
                              void* d_out, int out_size, void* d_ws, size_t ws_size,
                              hipStream_t stream) {
  const float* x     = (const float*)d_in[0];
  const int*   fb    = (const int*)d_in[1];
  const float* inW   = (const float*)d_in[2];
  const float* inb   = (const float*)d_in[3];
  const float* tkWy  = (const float*)d_in[4];
  const float* tkWq  = (const float*)d_in[5];
  const float* tkWk  = (const float*)d_in[6];
  const float* tkwb  = (const float*)d_in[7];
  const float* tklng = (const float*)d_in[8];
  const float* tklnb = (const float*)d_in[9];
  const float* tkmg  = (const float*)d_in[10];
  const float* tkmb  = (const float*)d_in[11];
  const float* tkmW1 = (const float*)d_in[12];
  const float* tkmb1 = (const float*)d_in[13];
  const float* tkmW2 = (const float*)d_in[14];
  const float* tkmb2 = (const float*)d_in[15];
  const float* chWy  = (const float*)d_in[16];
  const float* chWq  = (const float*)d_in[17];
  const float* chWk  = (const float*)d_in[18];
  const float* chwb  = (const float*)d_in[19];
  const float* chlng = (const float*)d_in[20];
  const float* chlnb = (const float*)d_in[21];
  const float* chmg  = (const float*)d_in[22];
  const float* chmb  = (const float*)d_in[23];
  const float* chmW1 = (const float*)d_in[24];
  const float* chmb1 = (const float*)d_in[25];
  const float* chmW2 = (const float*)d_in[26];
  const float* chmb2 = (const float*)d_in[27];
  const float* flng  = (const float*)d_in[28];
  const float* flnb  = (const float*)d_in[29];
  const float* oWy   = (const float*)d_in[30];
  const float* oWq   = (const float*)d_in[31];
  const float* oWk   = (const float*)d_in[32];
  const float* owb   = (const float*)d_in[33];
  const float* olng  = (const float*)d_in[34];
  const float* olnb  = (const float*)d_in[35];
  const float* outW  = (const float*)d_in[36];
  const float* outb  = (const float*)d_in[37];

  float* h    = (float*)d_ws;                               // (S,B,P,D) 2 MB
  float* gbuf = h + (size_t)cS * cB * cP * cD;              // (S,B,D)
  float* y2   = gbuf + (size_t)cS * cB * cD;                // (S,B,P,D) 2 MB scratch
  float* outp = (float*)d_out;                              // (S,B,NC)

  k_embed<<<dim3(cS * cB * cP), dim3(256), 0, stream>>>(x, fb, inW, inb, h);
  for (int i = 0; i < 2; ++i) {
    k_tok_srwm<<<dim3(256), dim3(128), 0, stream>>>(
        h, tkWy + i * 256, tkWq + i * 256, tkWk + i * 256, tkwb + i * 64,
        tklng + i * 16, tklnb + i * 16);
    k_tok_mixer<<<dim3(cS * cB), dim3(256), 0, stream>>>(
        h, tkmg + i * 256, tkmb + i * 256, tkmW1 + i * 1024, tkmb1 + i * 64,
        tkmW2 + i * 1024, tkmb2 + i * 16);
    k_ch_scan<<<dim3(cB * cP * 2), dim3(128), 0, stream>>>(
        h, y2, chWy + i * 4096, chWq + i * 4096, chWk + i * 4096, chwb + i * 1024);
    k_ch_ln_mix<<<dim3(cS * cB * cP / 8), dim3(256), 0, stream>>>(
        y2, h, chlng + i * 256, chlnb + i * 256,
        chmg + i * 256, chmb + i * 256, chmW1 + i * 32768, chmb1 + i * 128,
        chmW2 + i * 32768, chmb2 + i * 256);
  }
  k_fln_mean<<<dim3(cS * cB), dim3(256), 0, stream>>>(h, flng, flnb, gbuf);
  k_out_srwm<<<dim3(cB), dim3(256), 0, stream>>>(
      gbuf, outp, oWy, oWq, oWk, owb, olng, olnb, outW, outb);
}